// Round 4
// baseline (208.006 us; speedup 1.0000x reference)
//
#include <hip/hip_runtime.h>
#include <math.h>

#define Nn 50000
#define Ee 400000
#define FSz 256
#define HD_ 512
#define Bb 1024
#define HSZ 2048

// World model (settled R5/R6): ALL float inputs fp32; OUTPUT fp32.
static __device__ __forceinline__ int clampi(int v, int lo, int hi){
    return v < lo ? lo : (v > hi ? hi : v);
}
static __device__ __forceinline__ unsigned short f2bf(float f){
    unsigned int u = __float_as_uint(f);
    unsigned int r = u + 0x7FFFu + ((u >> 16) & 1u);
    return (unsigned short)(r >> 16);
}
static __device__ __forceinline__ float bflo(unsigned int v){ return __uint_as_float(v << 16); }
static __device__ __forceinline__ float bfhi(unsigned int v){ return __uint_as_float(v & 0xFFFF0000u); }

// K1: blocks 0-1562: edge scatter via per-block LDS hash of url.
//     blocks 1563-1578: parallel fold attn -> wl,wr [8][256].
//     blocks 1579-1610: convert Wfc/Wres to packed bf16 pairs (col 2t|2t+1).
__global__ __launch_bounds__(256) void k_scatter(const int* __restrict__ src, const int* __restrict__ dst,
                                                 const int* __restrict__ url,
                                                 int* __restrict__ fill, int* __restrict__ slist,
                                                 const float* __restrict__ W,
                                                 const float* __restrict__ al,
                                                 const float* __restrict__ ar,
                                                 float* __restrict__ wl, float* __restrict__ wr,
                                                 const float* __restrict__ Wfc,
                                                 const float* __restrict__ Wres,
                                                 unsigned int* __restrict__ wfcb,
                                                 unsigned int* __restrict__ wresb){
    int t = threadIdx.x;
    if(blockIdx.x >= 1579){
        // bf16-pack Wfc and Wres: out[f*256+c] = pack(bf(W[f*512+2c]), bf(W[f*512+2c+1]))
        int bi = blockIdx.x - 1579;           // 0..31
        int m = bi >> 4;                      // 0: Wfc, 1: Wres
        const float2* Sf = (const float2*)(m ? Wres : Wfc);
        unsigned int* D = m ? wresb : wfcb;
        int base = (bi & 15) * 8192;          // 16 blocks x 8192 = 131072 pairs
        #pragma unroll
        for(int i = 0; i < 32; i++){
            int idx = base + i*256 + t;
            float2 v = Sf[idx];               // pair (2c, 2c+1) of row f
            D[idx] = ((unsigned int)f2bf(v.y) << 16) | (unsigned int)f2bf(v.x);
        }
        return;
    }
    if(blockIdx.x >= 1563){
        int bi = blockIdx.x - 1563;       // 0..15
        int wv = t >> 6, lane = t & 63;
        #pragma unroll
        for(int r = 0; r < 4; r++){
            int f = bi*16 + wv*4 + r;
            float pl[8], pr[8];
            #pragma unroll
            for(int h = 0; h < 8; h++){
                float w = W[f*512 + h*64 + lane];
                pl[h] = w * al[h*64 + lane];
                pr[h] = w * ar[h*64 + lane];
            }
            #pragma unroll
            for(int h = 0; h < 8; h++){
                #pragma unroll
                for(int m = 32; m >= 1; m >>= 1){
                    pl[h] += __shfl_xor(pl[h], m, 64);
                    pr[h] += __shfl_xor(pr[h], m, 64);
                }
            }
            #pragma unroll
            for(int h = 0; h < 8; h++){
                if(lane == h){ wl[h*256 + f] = pl[h]; wr[h*256 + f] = pr[h]; }
            }
        }
        return;
    }
    __shared__ int key[HSZ];
    __shared__ int chainhead[HSZ];
    __shared__ short nxt[Bb];
    for(int i = t; i < HSZ; i += 256){ key[i] = -1; chainhead[i] = -1; }
    __syncthreads();
    for(int b = t; b < Bb; b += 256){
        int n = clampi(url[b] - 1, 0, Nn - 1);
        int h = n & (HSZ - 1);
        while(true){
            int prev = atomicCAS(&key[h], -1, n);
            if(prev == -1 || prev == n) break;
            h = (h + 1) & (HSZ - 1);
        }
        int old = atomicExch(&chainhead[h], b);
        nxt[b] = (short)old;
    }
    __syncthreads();
    int e = blockIdx.x * 256 + t;
    if(e >= Ee) return;
    int d = dst[e];
    if((unsigned)d >= (unsigned)Nn) return;
    int h = d & (HSZ - 1);
    while(true){
        int k = key[h];
        if(k == -1) return;
        if(k == d) break;
        h = (h + 1) & (HSZ - 1);
    }
    int s = clampi(src[e], 0, Nn - 1);
    for(int b = chainhead[h]; b != -1; b = nxt[b]){
        int pos = atomicAdd(&fill[b], 1);
        if(pos < 64) slist[b*64 + pos] = s;
    }
}

// K3: 2 slots/block, grid 512. GEMV weights now packed bf16 pairs (halves the
// 1 MB/block L2 weight stream that floored k_gat).
__global__ __launch_bounds__(256) void k_gat(const float* __restrict__ features,
                                             const unsigned int* __restrict__ Wfcb,   // [256][256] bf16 pairs
                                             const unsigned int* __restrict__ Wresb,
                                             const float* __restrict__ bias,
                                             const float* __restrict__ wl,   // [8][256] transposed
                                             const float* __restrict__ wr,
                                             const int* __restrict__ url,
                                             const int* __restrict__ fill, const int* __restrict__ slist,
                                             float* __restrict__ gemb){
    int t = threadIdx.x;
    int lane = t & 63, wv = t >> 6;
    int u0 = blockIdx.x * 2;

    __shared__ float cxs[2][8][256];
    __shared__ float fres[2][256];
    __shared__ float sew[2][64][8];
    __shared__ float ser[2][8];
    __shared__ int   sslist[2][64];

    for(int i = t; i < 2*64*8; i += 256) ((float*)sew)[i] = 0.f;

    float4 rwl[8], rwr[8];
    #pragma unroll
    for(int h = 0; h < 8; h++){
        rwl[h] = *(const float4*)&wl[h*256 + 4*lane];
        rwr[h] = *(const float4*)&wr[h*256 + 4*lane];
    }

    int dg[2], nj[2];
    #pragma unroll
    for(int j = 0; j < 2; j++){
        int u = u0 + j;
        dg[j] = min(fill[u], 64);
        nj[j] = clampi(url[u] - 1, 0, Nn - 1);
        if(t < dg[j]) sslist[j][t] = slist[u*64 + t];
        fres[j][t] = features[(size_t)nj[j] * FSz + t];
    }
    __syncthreads();

    // ---- pass A: wave-level dot products; tasks = all edges + 2 er rows
    int c1 = dg[0];
    int total = c1 + dg[1];
    for(int tau = wv; tau < total + 2; tau += 4){
        int j, i, isEr = 0;
        if(tau < c1){ j = 0; i = tau; }
        else if(tau < total){ j = 1; i = tau - c1; }
        else { j = tau - total; i = 0; isEr = 1; }
        int s = isEr ? nj[j] : sslist[j][i];
        float4 x = *(const float4*)(features + (size_t)s * FSz + 4*lane);
        float p[8];
        if(isEr){
            #pragma unroll
            for(int h = 0; h < 8; h++)
                p[h] = x.x*rwr[h].x + x.y*rwr[h].y + x.z*rwr[h].z + x.w*rwr[h].w;
        } else {
            #pragma unroll
            for(int h = 0; h < 8; h++)
                p[h] = x.x*rwl[h].x + x.y*rwl[h].y + x.z*rwl[h].z + x.w*rwl[h].w;
        }
        #pragma unroll
        for(int h = 0; h < 8; h++){
            #pragma unroll
            for(int m = 32; m >= 1; m >>= 1) p[h] += __shfl_xor(p[h], m, 64);
        }
        if(lane == 0){
            if(isEr){
                #pragma unroll
                for(int h = 0; h < 8; h++) ser[j][h] = p[h];
            } else {
                #pragma unroll
                for(int h = 0; h < 8; h++) sew[j][i][h] = p[h];
            }
        }
    }
    __syncthreads();
    // ---- softmax per (slot, head)
    if(t < 16){
        int j = t >> 3, h = t & 7;
        int dgj = dg[j];
        if(dgj > 0){
            float ern = ser[j][h];
            float m = -1e30f;
            for(int i = 0; i < dgj; i++){
                float v = sew[j][i][h] + ern;
                v = v > 0.f ? v : 0.2f * v;
                m = fmaxf(m, v);
            }
            float sum = 0.f;
            for(int i = 0; i < dgj; i++){
                float v = sew[j][i][h] + ern;
                v = v > 0.f ? v : 0.2f * v;
                float w = expf(v - m);
                sum += w;
                sew[j][i][h] = w;
            }
            float inv = 1.0f / fmaxf(sum, 1e-20f);
            for(int i = 0; i < dgj; i++) sew[j][i][h] *= inv;
        }
    }
    __syncthreads();
    // ---- pass B: alpha-combine; 2 slots x unroll 2 -> 4 gathers in flight
    {
        float cx[2][8];
        #pragma unroll
        for(int j = 0; j < 2; j++)
            #pragma unroll
            for(int h = 0; h < 8; h++) cx[j][h] = 0.f;
        int mxd = max(dg[0], dg[1]);
        for(int i = 0; i < mxd; i += 2){
            float x[2][2];
            #pragma unroll
            for(int j = 0; j < 2; j++)
                #pragma unroll
                for(int ii = 0; ii < 2; ii++){
                    int idx = i + ii;
                    int s = (idx < dg[j]) ? sslist[j][idx] : 0;
                    x[j][ii] = features[(size_t)s * FSz + t];
                }
            #pragma unroll
            for(int j = 0; j < 2; j++)
                #pragma unroll
                for(int ii = 0; ii < 2; ii++){
                    int idx = i + ii;
                    const float* av = &sew[j][idx < 64 ? idx : 0][0];
                    float xm = (idx < dg[j]) ? x[j][ii] : 0.f;
                    #pragma unroll
                    for(int h = 0; h < 8; h++) cx[j][h] += av[h] * xm;
                }
        }
        #pragma unroll
        for(int j = 0; j < 2; j++)
            #pragma unroll
            for(int h = 0; h < 8; h++) cxs[j][h][t] = cx[j][h];
    }
    __syncthreads();

    // ---- dual GEMV, bf16-pair weights (half the L2 bytes)
    int h = t >> 5;
    int o0 = 2 * t;
    float a[2][2] = {{0,0},{0,0}};
    for(int f = 0; f < 256; f += 4){
        unsigned int w0 = Wfcb[(f+0)*256 + t];
        unsigned int w1 = Wfcb[(f+1)*256 + t];
        unsigned int w2 = Wfcb[(f+2)*256 + t];
        unsigned int w3 = Wfcb[(f+3)*256 + t];
        unsigned int r0 = Wresb[(f+0)*256 + t];
        unsigned int r1 = Wresb[(f+1)*256 + t];
        unsigned int r2 = Wresb[(f+2)*256 + t];
        unsigned int r3 = Wresb[(f+3)*256 + t];
        #pragma unroll
        for(int j = 0; j < 2; j++){
            float4 c = *(const float4*)&cxs[j][h][f];
            float4 x = *(const float4*)&fres[j][f];
            a[j][0] += c.x*bflo(w0) + c.y*bflo(w1) + c.z*bflo(w2) + c.w*bflo(w3)
                     + x.x*bflo(r0) + x.y*bflo(r1) + x.z*bflo(r2) + x.w*bflo(r3);
            a[j][1] += c.x*bfhi(w0) + c.y*bfhi(w1) + c.z*bfhi(w2) + c.w*bfhi(w3)
                     + x.x*bfhi(r0) + x.y*bfhi(r1) + x.z*bfhi(r2) + x.w*bfhi(r3);
        }
    }
    float b0 = bias[o0], b1 = bias[o0 + 1];
    #pragma unroll
    for(int j = 0; j < 2; j++){
        float2* gp = (float2*)(gemb + (size_t)(u0 + j) * HD_);
        gp[t] = make_float2(a[j][0] + b0, a[j][1] + b1);
    }
}

// K4 (R15): 1 elem/block, grid 1024, __launch_bounds__(256,4).
// R13's 2-elem/512-block version was latency-bound: Occupancy 21% (grid cap
// = 2 blocks/CU), VALUBusy 35%, MfmaUtil 0, HBM 0.5% -> 65% of the 74 us was
// barrier idle. Halving per-block state (LDS 43.5->~22 KB, accumulators
// 96->48) and doubling the grid gives 4 blocks/CU (16 waves) so barriers of
// one block overlap compute of three others. Serial LN-stat (t<16 x 64-loop)
// and classifier (t<4 x 64-loop) sections replaced with shuffle reductions.
__global__ __launch_bounds__(256, 4) void k_mha(const float* __restrict__ gemb,
                                             const float* __restrict__ lng, const float* __restrict__ lnb,
                                             const float* __restrict__ wq, const float* __restrict__ wk,
                                             const float* __restrict__ wvp, const float* __restrict__ fcw,
                                             const float* __restrict__ fcb, const float* __restrict__ mlg,
                                             const float* __restrict__ mlb, const float* __restrict__ outw,
                                             const float* __restrict__ outb, float* __restrict__ out){
    __shared__ float A[512];                 // xr -> sc -> yy
    __shared__ float xnF[512];               // fp32 LN1 out (residual)
    __shared__ unsigned short xnT[512];      // bf16 LN1 out, [d*8+q]
    __shared__ unsigned short qkb[8320];     // bf16 q | k ; k-region reused for fp32 partials
    __shared__ float mu8[8], rs8[8], pooled[64];

    int t = threadIdx.x;
    int wv = t >> 6;
    int e = blockIdx.x;

    {
        const float* g0 = gemb + (size_t)e * HD_;
        A[t] = g0[t]; A[t + 256] = g0[t + 256];
    }
    __syncthreads();
    // ---- LN1 stats: wave 0, 8 lanes per q-row, shuffle-reduced ----
    if(t < 64){
        int q = t >> 3, d0 = t & 7;
        float s = 0.f, s2 = 0.f;
        #pragma unroll
        for(int k = 0; k < 8; k++){ float v = A[q*64 + d0 + 8*k]; s += v; s2 += v * v; }
        #pragma unroll
        for(int m = 1; m <= 4; m <<= 1){ s += __shfl_xor(s, m, 64); s2 += __shfl_xor(s2, m, 64); }
        if(d0 == 0){
            float mu = s * (1.0f/64.0f);
            float var = s2 * (1.0f/64.0f) - mu * mu;
            mu8[q] = mu; rs8[q] = rsqrtf(fmaxf(var, 0.0f) + 1e-6f);
        }
    }
    __syncthreads();
    #pragma unroll
    for(int p = 0; p < 2; p++){
        int i = p*256 + t; int q = i >> 6, d = i & 63;
        float xv = (A[i] - mu8[q]) * rs8[q] * lng[d] + lnb[d];
        xnF[i] = xv;
        xnT[d*8 + q] = f2bf(xv);
    }
    __syncthreads();
    // ---- fused q,k,v projection; thread owns cols t, t+256 ----
    float aq0[8], aq1[8], ak0[8], ak1[8], av0[8], av1[8];
    #pragma unroll
    for(int r = 0; r < 8; r++){
        aq0[r]=0.f; aq1[r]=0.f; ak0[r]=0.f;
        ak1[r]=0.f; av0[r]=0.f; av1[r]=0.f;
    }
    #pragma unroll 2
    for(int d = 0; d < 64; d++){
        float q0 = wq[d*512 + t],  q1 = wq[d*512 + t + 256];
        float k0 = wk[d*512 + t],  k1 = wk[d*512 + t + 256];
        float v0 = wvp[d*512 + t], v1 = wvp[d*512 + t + 256];
        uint4 xp = *(const uint4*)&xnT[d*8];
        float xv[8] = { bflo(xp.x), bfhi(xp.x), bflo(xp.y), bfhi(xp.y),
                        bflo(xp.z), bfhi(xp.z), bflo(xp.w), bfhi(xp.w) };
        #pragma unroll
        for(int r = 0; r < 8; r++){
            aq0[r] += xv[r]*q0; aq1[r] += xv[r]*q1;
            ak0[r] += xv[r]*k0; ak1[r] += xv[r]*k1;
            av0[r] += xv[r]*v0; av1[r] += xv[r]*v1;
        }
    }
    #pragma unroll
    for(int qq = 0; qq < 8; qq++){
        qkb[qq*520 + t]              = f2bf(aq0[qq]);
        qkb[qq*520 + t + 256]        = f2bf(aq1[qq]);
        qkb[4160 + qq*520 + t]       = f2bf(ak0[qq]);
        qkb[4160 + qq*520 + t + 256] = f2bf(ak1[qq]);
    }
    __syncthreads();
    // ---- scores: 512 tasks, 2 per thread ----
    #pragma unroll
    for(int p = 0; p < 2; p++){
        int idx = p*256 + t;
        int nh = idx >> 6, qq = (idx >> 3) & 7, kk = idx & 7;
        const unsigned short* qrow = &qkb[qq*520 + nh*64];
        const unsigned short* krow = &qkb[4160 + kk*520 + nh*64];
        float s = 0.f;
        #pragma unroll
        for(int d8 = 0; d8 < 64; d8 += 8){
            uint4 qv = *(const uint4*)&qrow[d8];
            uint4 kv = *(const uint4*)&krow[d8];
            s += bflo(qv.x)*bflo(kv.x) + bfhi(qv.x)*bfhi(kv.x)
               + bflo(qv.y)*bflo(kv.y) + bfhi(qv.y)*bfhi(kv.y)
               + bflo(qv.z)*bflo(kv.z) + bfhi(qv.z)*bfhi(kv.z)
               + bflo(qv.w)*bflo(kv.w) + bfhi(qv.w)*bfhi(kv.w);
        }
        A[idx] = s * 0.125f;
    }
    __syncthreads();
    if(t < 64){
        int row = t;
        float mx = -1e30f;
        #pragma unroll
        for(int k = 0; k < 8; k++) mx = fmaxf(mx, A[row*8 + k]);
        float ev[8]; float s = 0.f;
        #pragma unroll
        for(int k = 0; k < 8; k++){ ev[k] = expf(A[row*8 + k] - mx); s += ev[k]; }
        float inv = 1.0f / s;
        #pragma unroll
        for(int k = 0; k < 8; k++) A[row*8 + k] = ev[k] * inv;
    }
    __syncthreads();
    // ---- attn @ v (v in registers) -> ov (bf16) into q regions ----
    {
        int nh0 = wv;
        #pragma unroll
        for(int qq = 0; qq < 8; qq++){
            const float* s0 = &A[nh0*64 + qq*8];
            const float* s1 = &A[(nh0+4)*64 + qq*8];
            float4 a0 = *(const float4*)s0, b0 = *(const float4*)(s0 + 4);
            float4 a1 = *(const float4*)s1, b1 = *(const float4*)(s1 + 4);
            float o0 = a0.x*av0[0] + a0.y*av0[1] + a0.z*av0[2] + a0.w*av0[3]
                     + b0.x*av0[4] + b0.y*av0[5] + b0.z*av0[6] + b0.w*av0[7];
            float o1 = a1.x*av1[0] + a1.y*av1[1] + a1.z*av1[2] + a1.w*av1[3]
                     + b1.x*av1[4] + b1.y*av1[5] + b1.z*av1[6] + b1.w*av1[7];
            qkb[qq*520 + t]       = f2bf(o0);
            qkb[qq*520 + t + 256] = f2bf(o1);
        }
    }
    __syncthreads();
    // ---- fc wave-split: wave wv owns k-range [wv*128, wv*128+128) ----
    {
        float* P = (float*)&qkb[4160];        // 4 waves x 512 fp32 partials
        int g = (t & 63) & 31;
        int qh = (t & 63) >> 5;
        int k0r = wv * 128;
        float a[4][2];
        #pragma unroll
        for(int jq = 0; jq < 4; jq++){ a[jq][0] = 0.f; a[jq][1] = 0.f; }
        const float2* fw2 = (const float2*)fcw;   // [512][32] float2
        for(int k = k0r; k < k0r + 128; k += 8){
            float2 f0 = fw2[(k+0)*32 + g];
            float2 f1 = fw2[(k+1)*32 + g];
            float2 f2 = fw2[(k+2)*32 + g];
            float2 f3 = fw2[(k+3)*32 + g];
            float2 f4 = fw2[(k+4)*32 + g];
            float2 f5 = fw2[(k+5)*32 + g];
            float2 f6 = fw2[(k+6)*32 + g];
            float2 f7 = fw2[(k+7)*32 + g];
            #pragma unroll
            for(int jq = 0; jq < 4; jq++){
                int qq = qh*4 + jq;
                uint4 op = *(const uint4*)&qkb[qq*520 + k];
                float x0 = bflo(op.x), x1 = bfhi(op.x), x2 = bflo(op.y), x3 = bfhi(op.y);
                float x4 = bflo(op.z), x5 = bfhi(op.z), x6 = bflo(op.w), x7 = bfhi(op.w);
                a[jq][0] += x0*f0.x + x1*f1.x + x2*f2.x + x3*f3.x + x4*f4.x + x5*f5.x + x6*f6.x + x7*f7.x;
                a[jq][1] += x0*f0.y + x1*f1.y + x2*f2.y + x3*f3.y + x4*f4.y + x5*f5.y + x6*f6.y + x7*f7.y;
            }
        }
        __syncthreads();
        #pragma unroll
        for(int jq = 0; jq < 4; jq++){
            int qq = qh*4 + jq;
            *(float2*)&P[wv*512 + qq*64 + 2*g] = make_float2(a[jq][0], a[jq][1]);
        }
        __syncthreads();
        #pragma unroll
        for(int p = 0; p < 2; p++){
            int o = p*256 + t; int dd = o & 63;
            A[o] = P[o] + P[512 + o] + P[1024 + o] + P[1536 + o] + fcb[dd] + xnF[o];
        }
    }
    __syncthreads();
    // ---- LN2 stats: wave-parallel like LN1 ----
    if(t < 64){
        int q = t >> 3, d0 = t & 7;
        float s = 0.f, s2 = 0.f;
        #pragma unroll
        for(int k = 0; k < 8; k++){ float v = A[q*64 + d0 + 8*k]; s += v; s2 += v * v; }
        #pragma unroll
        for(int m = 1; m <= 4; m <<= 1){ s += __shfl_xor(s, m, 64); s2 += __shfl_xor(s2, m, 64); }
        if(d0 == 0){
            float mu = s * (1.0f/64.0f);
            float var = s2 * (1.0f/64.0f) - mu * mu;
            mu8[q] = mu; rs8[q] = rsqrtf(fmaxf(var, 0.0f) + 1e-6f);
        }
    }
    __syncthreads();
    if(t < 64){
        int dd = t;
        float g2 = mlg[dd], bb = mlb[dd];
        float s = 0.f;
        #pragma unroll
        for(int qq = 0; qq < 8; qq++)
            s += (A[qq*64 + dd] - mu8[qq]) * rs8[qq] * g2 + bb;
        pooled[dd] = s;
    }
    __syncthreads();
    // ---- classifier: 2 output cols x 64-lane shuffle reduce ----
    if(t < 128){
        int c = t >> 6, d = t & 63;
        float v = pooled[d] * outw[d*2 + c];
        #pragma unroll
        for(int m = 32; m >= 1; m >>= 1) v += __shfl_xor(v, m, 64);
        if((t & 63) == 0) out[e*2 + c] = v + outb[c];
    }
}

extern "C" void kernel_launch(void* const* d_in, const int* in_sizes, int n_in,
                              void* d_out, int out_size, void* d_ws, size_t ws_size,
                              hipStream_t stream){
    (void)in_sizes; (void)n_in; (void)out_size; (void)ws_size;
    const float* features  = (const float*)d_in[0];
    const int*   src       = (const int*)d_in[1];
    const int*   dst       = (const int*)d_in[2];
    const int*   url       = (const int*)d_in[3];
    const float* gat_fc_w  = (const float*)d_in[4];
    const float* attn_l    = (const float*)d_in[5];
    const float* attn_r    = (const float*)d_in[6];
    const float* gat_res_w = (const float*)d_in[7];
    const float* gat_bias  = (const float*)d_in[8];
    const float* ln_g      = (const float*)d_in[9];
    const float* ln_b      = (const float*)d_in[10];
    const float* wq        = (const float*)d_in[11];
    const float* wk        = (const float*)d_in[12];
    const float* wv        = (const float*)d_in[13];
    const float* fc_w      = (const float*)d_in[14];
    const float* fc_b      = (const float*)d_in[15];
    const float* mha_ln_g  = (const float*)d_in[16];
    const float* mha_ln_b  = (const float*)d_in[17];
    const float* out_w     = (const float*)d_in[18];
    const float* out_b     = (const float*)d_in[19];

    char* base = (char*)d_ws;
    size_t cur = 0;
    auto alloc = [&](size_t nbytes) -> void* {
        void* p = base + cur;
        cur = (cur + nbytes + 255) & ~(size_t)255;
        return p;
    };
    float*        wl    = (float*)alloc(2048 * sizeof(float));   // transposed [8][256]
    float*        wr    = (float*)alloc(2048 * sizeof(float));
    int*          fill  = (int*)alloc(1024 * sizeof(int));
    int*          slist = (int*)alloc((size_t)1024 * 64 * sizeof(int));
    float*        gemb  = (float*)alloc((size_t)1024 * 512 * sizeof(float));
    unsigned int* wfcb  = (unsigned int*)alloc((size_t)256 * 512 * sizeof(unsigned short));
    unsigned int* wresb = (unsigned int*)alloc((size_t)256 * 512 * sizeof(unsigned short));

    hipMemsetAsync(fill, 0, 1024 * sizeof(int), stream);

    hipLaunchKernelGGL(k_scatter, dim3(1611), dim3(256), 0, stream, src, dst, url, fill, slist,
                       gat_fc_w, attn_l, attn_r, wl, wr, gat_fc_w, gat_res_w, wfcb, wresb);
    hipLaunchKernelGGL(k_gat,     dim3(512),  dim3(256), 0, stream, features, wfcb, wresb, gat_bias,
                       wl, wr, url, fill, slist, gemb);
    hipLaunchKernelGGL(k_mha,     dim3(1024), dim3(256), 0, stream, gemb, ln_g, ln_b,
                       wq, wk, wv, fc_w, fc_b, mha_ln_g, mha_ln_b, out_w, out_b,
                       (float*)d_out);
}

// Round 5
// 202.093 us; speedup vs baseline: 1.0293x; 1.0293x over previous
//
#include <hip/hip_runtime.h>
#include <math.h>

#define Nn 50000
#define Ee 400000
#define FSz 256
#define HD_ 512
#define Bb 1024
#define HSZ 2048

// World model (settled R5/R6): ALL float inputs fp32; OUTPUT fp32.
static __device__ __forceinline__ int clampi(int v, int lo, int hi){
    return v < lo ? lo : (v > hi ? hi : v);
}
static __device__ __forceinline__ unsigned short f2bf(float f){
    unsigned int u = __float_as_uint(f);
    unsigned int r = u + 0x7FFFu + ((u >> 16) & 1u);
    return (unsigned short)(r >> 16);
}
static __device__ __forceinline__ float bflo(unsigned int v){ return __uint_as_float(v << 16); }
static __device__ __forceinline__ float bfhi(unsigned int v){ return __uint_as_float(v & 0xFFFF0000u); }

// K1: blocks 0-1562: edge scatter via per-block LDS hash of url.
//     blocks 1563-1578: parallel fold attn -> wl,wr [8][256].
//     blocks 1579-1610: convert Wfc/Wres to packed bf16 pairs (col 2t|2t+1).
__global__ __launch_bounds__(256) void k_scatter(const int* __restrict__ src, const int* __restrict__ dst,
                                                 const int* __restrict__ url,
                                                 int* __restrict__ fill, int* __restrict__ slist,
                                                 const float* __restrict__ W,
                                                 const float* __restrict__ al,
                                                 const float* __restrict__ ar,
                                                 float* __restrict__ wl, float* __restrict__ wr,
                                                 const float* __restrict__ Wfc,
                                                 const float* __restrict__ Wres,
                                                 unsigned int* __restrict__ wfcb,
                                                 unsigned int* __restrict__ wresb){
    int t = threadIdx.x;
    if(blockIdx.x >= 1579){
        // bf16-pack Wfc and Wres: out[f*256+c] = pack(bf(W[f*512+2c]), bf(W[f*512+2c+1]))
        int bi = blockIdx.x - 1579;           // 0..31
        int m = bi >> 4;                      // 0: Wfc, 1: Wres
        const float2* Sf = (const float2*)(m ? Wres : Wfc);
        unsigned int* D = m ? wresb : wfcb;
        int base = (bi & 15) * 8192;          // 16 blocks x 8192 = 131072 pairs
        #pragma unroll
        for(int i = 0; i < 32; i++){
            int idx = base + i*256 + t;
            float2 v = Sf[idx];               // pair (2c, 2c+1) of row f
            D[idx] = ((unsigned int)f2bf(v.y) << 16) | (unsigned int)f2bf(v.x);
        }
        return;
    }
    if(blockIdx.x >= 1563){
        int bi = blockIdx.x - 1563;       // 0..15
        int wv = t >> 6, lane = t & 63;
        #pragma unroll
        for(int r = 0; r < 4; r++){
            int f = bi*16 + wv*4 + r;
            float pl[8], pr[8];
            #pragma unroll
            for(int h = 0; h < 8; h++){
                float w = W[f*512 + h*64 + lane];
                pl[h] = w * al[h*64 + lane];
                pr[h] = w * ar[h*64 + lane];
            }
            #pragma unroll
            for(int h = 0; h < 8; h++){
                #pragma unroll
                for(int m = 32; m >= 1; m >>= 1){
                    pl[h] += __shfl_xor(pl[h], m, 64);
                    pr[h] += __shfl_xor(pr[h], m, 64);
                }
            }
            #pragma unroll
            for(int h = 0; h < 8; h++){
                if(lane == h){ wl[h*256 + f] = pl[h]; wr[h*256 + f] = pr[h]; }
            }
        }
        return;
    }
    __shared__ int key[HSZ];
    __shared__ int chainhead[HSZ];
    __shared__ short nxt[Bb];
    for(int i = t; i < HSZ; i += 256){ key[i] = -1; chainhead[i] = -1; }
    __syncthreads();
    for(int b = t; b < Bb; b += 256){
        int n = clampi(url[b] - 1, 0, Nn - 1);
        int h = n & (HSZ - 1);
        while(true){
            int prev = atomicCAS(&key[h], -1, n);
            if(prev == -1 || prev == n) break;
            h = (h + 1) & (HSZ - 1);
        }
        int old = atomicExch(&chainhead[h], b);
        nxt[b] = (short)old;
    }
    __syncthreads();
    int e = blockIdx.x * 256 + t;
    if(e >= Ee) return;
    int d = dst[e];
    if((unsigned)d >= (unsigned)Nn) return;
    int h = d & (HSZ - 1);
    while(true){
        int k = key[h];
        if(k == -1) return;
        if(k == d) break;
        h = (h + 1) & (HSZ - 1);
    }
    int s = clampi(src[e], 0, Nn - 1);
    for(int b = chainhead[h]; b != -1; b = nxt[b]){
        int pos = atomicAdd(&fill[b], 1);
        if(pos < 64) slist[b*64 + pos] = s;
    }
}

// K3 (R16): 1 slot/block, grid 1024, __launch_bounds__(256,4).
// R4 profile: k_gat cold dispatch 143 us at Occupancy 1.3%, VALUBusy 2.4%,
// HBM 0.9% -> avg block finishes in ~7 us but stragglers run ~140 us; grid
// 512 = 2 blocks/CU cap left nothing co-resident to hide gather latency
// (same disease k_mha had). 1 slot/block halves LDS (23.5->11.6 KB) and
// per-block gather work -> 4 blocks/CU: GEMV of one block overlaps gather
// latency of others, straggler tail halves. Weight L2 traffic doubles
// (512 KB/block x 1024) -- same trade k_mha made and won. Softmax
// wave-parallelized (8 lanes/head, shuffle reduce) to cut high-dg tails.
__global__ __launch_bounds__(256, 4) void k_gat(const float* __restrict__ features,
                                             const unsigned int* __restrict__ Wfcb,   // [256][256] bf16 pairs
                                             const unsigned int* __restrict__ Wresb,
                                             const float* __restrict__ bias,
                                             const float* __restrict__ wl,   // [8][256] transposed
                                             const float* __restrict__ wr,
                                             const int* __restrict__ url,
                                             const int* __restrict__ fill, const int* __restrict__ slist,
                                             float* __restrict__ gemb){
    int t = threadIdx.x;
    int lane = t & 63, wv = t >> 6;
    int u = blockIdx.x;

    __shared__ float cxs[8][256];    // 8 KB
    __shared__ float fres[256];      // 1 KB
    __shared__ float sew[64][8];     // 2 KB
    __shared__ float ser[8];
    __shared__ int   sslist[64];

    for(int i = t; i < 64*8; i += 256) ((float*)sew)[i] = 0.f;

    float4 rwl[8], rwr[8];
    #pragma unroll
    for(int h = 0; h < 8; h++){
        rwl[h] = *(const float4*)&wl[h*256 + 4*lane];
        rwr[h] = *(const float4*)&wr[h*256 + 4*lane];
    }

    int dg = min(fill[u], 64);
    int nj = clampi(url[u] - 1, 0, Nn - 1);
    if(t < dg) sslist[t] = slist[u*64 + t];
    fres[t] = features[(size_t)nj * FSz + t];
    __syncthreads();

    // ---- pass A: wave-level dot products; tasks = dg edges + 1 er row
    for(int tau = wv; tau < dg + 1; tau += 4){
        int isEr = (tau == dg);
        int s = isEr ? nj : sslist[tau];
        float4 x = *(const float4*)(features + (size_t)s * FSz + 4*lane);
        float p[8];
        if(isEr){
            #pragma unroll
            for(int h = 0; h < 8; h++)
                p[h] = x.x*rwr[h].x + x.y*rwr[h].y + x.z*rwr[h].z + x.w*rwr[h].w;
        } else {
            #pragma unroll
            for(int h = 0; h < 8; h++)
                p[h] = x.x*rwl[h].x + x.y*rwl[h].y + x.z*rwl[h].z + x.w*rwl[h].w;
        }
        #pragma unroll
        for(int h = 0; h < 8; h++){
            #pragma unroll
            for(int m = 32; m >= 1; m >>= 1) p[h] += __shfl_xor(p[h], m, 64);
        }
        if(lane == 0){
            if(isEr){
                #pragma unroll
                for(int h = 0; h < 8; h++) ser[h] = p[h];
            } else {
                #pragma unroll
                for(int h = 0; h < 8; h++) sew[tau][h] = p[h];
            }
        }
    }
    __syncthreads();
    // ---- softmax per head: 8 lanes/head, shuffle-reduced over the group
    if(t < 64){
        int h = t >> 3, il = t & 7;   // lanes h*8..h*8+7 share head h
        float ern = ser[h];
        float m = -1e30f;
        for(int i = il; i < dg; i += 8){
            float v = sew[i][h] + ern;
            v = v > 0.f ? v : 0.2f * v;
            m = fmaxf(m, v);
        }
        #pragma unroll
        for(int mm = 1; mm <= 4; mm <<= 1) m = fmaxf(m, __shfl_xor(m, mm, 64));
        float sum = 0.f;
        for(int i = il; i < dg; i += 8){
            float v = sew[i][h] + ern;
            v = v > 0.f ? v : 0.2f * v;
            float w = expf(v - m);
            sum += w;
            sew[i][h] = w;
        }
        #pragma unroll
        for(int mm = 1; mm <= 4; mm <<= 1) sum += __shfl_xor(sum, mm, 64);
        float inv = 1.0f / fmaxf(sum, 1e-20f);
        for(int i = il; i < dg; i += 8) sew[i][h] *= inv;
    }
    __syncthreads();
    // ---- pass B: alpha-combine; unroll 4 -> 4 gathers in flight
    {
        float cx[8];
        #pragma unroll
        for(int h = 0; h < 8; h++) cx[h] = 0.f;
        for(int i = 0; i < dg; i += 4){
            float x[4];
            #pragma unroll
            for(int ii = 0; ii < 4; ii++){
                int idx = i + ii;
                int s = (idx < dg) ? sslist[idx] : 0;
                x[ii] = features[(size_t)s * FSz + t];
            }
            #pragma unroll
            for(int ii = 0; ii < 4; ii++){
                int idx = i + ii;
                const float* av = &sew[idx < 64 ? idx : 0][0];
                float xm = (idx < dg) ? x[ii] : 0.f;
                #pragma unroll
                for(int h = 0; h < 8; h++) cx[h] += av[h] * xm;
            }
        }
        #pragma unroll
        for(int h = 0; h < 8; h++) cxs[h][t] = cx[h];
    }
    __syncthreads();

    // ---- GEMV, bf16-pair weights; thread owns output cols 2t, 2t+1
    int hh = t >> 5;
    float a0 = 0.f, a1 = 0.f;
    for(int f = 0; f < 256; f += 4){
        unsigned int w0 = Wfcb[(f+0)*256 + t];
        unsigned int w1 = Wfcb[(f+1)*256 + t];
        unsigned int w2 = Wfcb[(f+2)*256 + t];
        unsigned int w3 = Wfcb[(f+3)*256 + t];
        unsigned int r0 = Wresb[(f+0)*256 + t];
        unsigned int r1 = Wresb[(f+1)*256 + t];
        unsigned int r2 = Wresb[(f+2)*256 + t];
        unsigned int r3 = Wresb[(f+3)*256 + t];
        float4 c = *(const float4*)&cxs[hh][f];
        float4 x = *(const float4*)&fres[f];
        a0 += c.x*bflo(w0) + c.y*bflo(w1) + c.z*bflo(w2) + c.w*bflo(w3)
            + x.x*bflo(r0) + x.y*bflo(r1) + x.z*bflo(r2) + x.w*bflo(r3);
        a1 += c.x*bfhi(w0) + c.y*bfhi(w1) + c.z*bfhi(w2) + c.w*bfhi(w3)
            + x.x*bfhi(r0) + x.y*bfhi(r1) + x.z*bfhi(r2) + x.w*bfhi(r3);
    }
    float2* gp = (float2*)(gemb + (size_t)u * HD_);
    gp[t] = make_float2(a0 + bias[2*t], a1 + bias[2*t + 1]);
}

// K4 (R15): 1 elem/block, grid 1024, __launch_bounds__(256,4).
// R4 profile: dur 74->54.7 us, Occupancy 21->29%, VALUBusy 35->56%. Keep.
__global__ __launch_bounds__(256, 4) void k_mha(const float* __restrict__ gemb,
                                             const float* __restrict__ lng, const float* __restrict__ lnb,
                                             const float* __restrict__ wq, const float* __restrict__ wk,
                                             const float* __restrict__ wvp, const float* __restrict__ fcw,
                                             const float* __restrict__ fcb, const float* __restrict__ mlg,
                                             const float* __restrict__ mlb, const float* __restrict__ outw,
                                             const float* __restrict__ outb, float* __restrict__ out){
    __shared__ float A[512];                 // xr -> sc -> yy
    __shared__ float xnF[512];               // fp32 LN1 out (residual)
    __shared__ unsigned short xnT[512];      // bf16 LN1 out, [d*8+q]
    __shared__ unsigned short qkb[8320];     // bf16 q | k ; k-region reused for fp32 partials
    __shared__ float mu8[8], rs8[8], pooled[64];

    int t = threadIdx.x;
    int wv = t >> 6;
    int e = blockIdx.x;

    {
        const float* g0 = gemb + (size_t)e * HD_;
        A[t] = g0[t]; A[t + 256] = g0[t + 256];
    }
    __syncthreads();
    // ---- LN1 stats: wave 0, 8 lanes per q-row, shuffle-reduced ----
    if(t < 64){
        int q = t >> 3, d0 = t & 7;
        float s = 0.f, s2 = 0.f;
        #pragma unroll
        for(int k = 0; k < 8; k++){ float v = A[q*64 + d0 + 8*k]; s += v; s2 += v * v; }
        #pragma unroll
        for(int m = 1; m <= 4; m <<= 1){ s += __shfl_xor(s, m, 64); s2 += __shfl_xor(s2, m, 64); }
        if(d0 == 0){
            float mu = s * (1.0f/64.0f);
            float var = s2 * (1.0f/64.0f) - mu * mu;
            mu8[q] = mu; rs8[q] = rsqrtf(fmaxf(var, 0.0f) + 1e-6f);
        }
    }
    __syncthreads();
    #pragma unroll
    for(int p = 0; p < 2; p++){
        int i = p*256 + t; int q = i >> 6, d = i & 63;
        float xv = (A[i] - mu8[q]) * rs8[q] * lng[d] + lnb[d];
        xnF[i] = xv;
        xnT[d*8 + q] = f2bf(xv);
    }
    __syncthreads();
    // ---- fused q,k,v projection; thread owns cols t, t+256 ----
    float aq0[8], aq1[8], ak0[8], ak1[8], av0[8], av1[8];
    #pragma unroll
    for(int r = 0; r < 8; r++){
        aq0[r]=0.f; aq1[r]=0.f; ak0[r]=0.f;
        ak1[r]=0.f; av0[r]=0.f; av1[r]=0.f;
    }
    #pragma unroll 2
    for(int d = 0; d < 64; d++){
        float q0 = wq[d*512 + t],  q1 = wq[d*512 + t + 256];
        float k0 = wk[d*512 + t],  k1 = wk[d*512 + t + 256];
        float v0 = wvp[d*512 + t], v1 = wvp[d*512 + t + 256];
        uint4 xp = *(const uint4*)&xnT[d*8];
        float xv[8] = { bflo(xp.x), bfhi(xp.x), bflo(xp.y), bfhi(xp.y),
                        bflo(xp.z), bfhi(xp.z), bflo(xp.w), bfhi(xp.w) };
        #pragma unroll
        for(int r = 0; r < 8; r++){
            aq0[r] += xv[r]*q0; aq1[r] += xv[r]*q1;
            ak0[r] += xv[r]*k0; ak1[r] += xv[r]*k1;
            av0[r] += xv[r]*v0; av1[r] += xv[r]*v1;
        }
    }
    #pragma unroll
    for(int qq = 0; qq < 8; qq++){
        qkb[qq*520 + t]              = f2bf(aq0[qq]);
        qkb[qq*520 + t + 256]        = f2bf(aq1[qq]);
        qkb[4160 + qq*520 + t]       = f2bf(ak0[qq]);
        qkb[4160 + qq*520 + t + 256] = f2bf(ak1[qq]);
    }
    __syncthreads();
    // ---- scores: 512 tasks, 2 per thread ----
    #pragma unroll
    for(int p = 0; p < 2; p++){
        int idx = p*256 + t;
        int nh = idx >> 6, qq = (idx >> 3) & 7, kk = idx & 7;
        const unsigned short* qrow = &qkb[qq*520 + nh*64];
        const unsigned short* krow = &qkb[4160 + kk*520 + nh*64];
        float s = 0.f;
        #pragma unroll
        for(int d8 = 0; d8 < 64; d8 += 8){
            uint4 qv = *(const uint4*)&qrow[d8];
            uint4 kv = *(const uint4*)&krow[d8];
            s += bflo(qv.x)*bflo(kv.x) + bfhi(qv.x)*bfhi(kv.x)
               + bflo(qv.y)*bflo(kv.y) + bfhi(qv.y)*bfhi(kv.y)
               + bflo(qv.z)*bflo(kv.z) + bfhi(qv.z)*bfhi(kv.z)
               + bflo(qv.w)*bflo(kv.w) + bfhi(qv.w)*bfhi(kv.w);
        }
        A[idx] = s * 0.125f;
    }
    __syncthreads();
    if(t < 64){
        int row = t;
        float mx = -1e30f;
        #pragma unroll
        for(int k = 0; k < 8; k++) mx = fmaxf(mx, A[row*8 + k]);
        float ev[8]; float s = 0.f;
        #pragma unroll
        for(int k = 0; k < 8; k++){ ev[k] = expf(A[row*8 + k] - mx); s += ev[k]; }
        float inv = 1.0f / s;
        #pragma unroll
        for(int k = 0; k < 8; k++) A[row*8 + k] = ev[k] * inv;
    }
    __syncthreads();
    // ---- attn @ v (v in registers) -> ov (bf16) into q regions ----
    {
        int nh0 = wv;
        #pragma unroll
        for(int qq = 0; qq < 8; qq++){
            const float* s0 = &A[nh0*64 + qq*8];
            const float* s1 = &A[(nh0+4)*64 + qq*8];
            float4 a0 = *(const float4*)s0, b0 = *(const float4*)(s0 + 4);
            float4 a1 = *(const float4*)s1, b1 = *(const float4*)(s1 + 4);
            float o0 = a0.x*av0[0] + a0.y*av0[1] + a0.z*av0[2] + a0.w*av0[3]
                     + b0.x*av0[4] + b0.y*av0[5] + b0.z*av0[6] + b0.w*av0[7];
            float o1 = a1.x*av1[0] + a1.y*av1[1] + a1.z*av1[2] + a1.w*av1[3]
                     + b1.x*av1[4] + b1.y*av1[5] + b1.z*av1[6] + b1.w*av1[7];
            qkb[qq*520 + t]       = f2bf(o0);
            qkb[qq*520 + t + 256] = f2bf(o1);
        }
    }
    __syncthreads();
    // ---- fc wave-split: wave wv owns k-range [wv*128, wv*128+128) ----
    {
        float* P = (float*)&qkb[4160];        // 4 waves x 512 fp32 partials
        int g = (t & 63) & 31;
        int qh = (t & 63) >> 5;
        int k0r = wv * 128;
        float a[4][2];
        #pragma unroll
        for(int jq = 0; jq < 4; jq++){ a[jq][0] = 0.f; a[jq][1] = 0.f; }
        const float2* fw2 = (const float2*)fcw;   // [512][32] float2
        for(int k = k0r; k < k0r + 128; k += 8){
            float2 f0 = fw2[(k+0)*32 + g];
            float2 f1 = fw2[(k+1)*32 + g];
            float2 f2 = fw2[(k+2)*32 + g];
            float2 f3 = fw2[(k+3)*32 + g];
            float2 f4 = fw2[(k+4)*32 + g];
            float2 f5 = fw2[(k+5)*32 + g];
            float2 f6 = fw2[(k+6)*32 + g];
            float2 f7 = fw2[(k+7)*32 + g];
            #pragma unroll
            for(int jq = 0; jq < 4; jq++){
                int qq = qh*4 + jq;
                uint4 op = *(const uint4*)&qkb[qq*520 + k];
                float x0 = bflo(op.x), x1 = bfhi(op.x), x2 = bflo(op.y), x3 = bfhi(op.y);
                float x4 = bflo(op.z), x5 = bfhi(op.z), x6 = bflo(op.w), x7 = bfhi(op.w);
                a[jq][0] += x0*f0.x + x1*f1.x + x2*f2.x + x3*f3.x + x4*f4.x + x5*f5.x + x6*f6.x + x7*f7.x;
                a[jq][1] += x0*f0.y + x1*f1.y + x2*f2.y + x3*f3.y + x4*f4.y + x5*f5.y + x6*f6.y + x7*f7.y;
            }
        }
        __syncthreads();
        #pragma unroll
        for(int jq = 0; jq < 4; jq++){
            int qq = qh*4 + jq;
            *(float2*)&P[wv*512 + qq*64 + 2*g] = make_float2(a[jq][0], a[jq][1]);
        }
        __syncthreads();
        #pragma unroll
        for(int p = 0; p < 2; p++){
            int o = p*256 + t; int dd = o & 63;
            A[o] = P[o] + P[512 + o] + P[1024 + o] + P[1536 + o] + fcb[dd] + xnF[o];
        }
    }
    __syncthreads();
    // ---- LN2 stats: wave-parallel like LN1 ----
    if(t < 64){
        int q = t >> 3, d0 = t & 7;
        float s = 0.f, s2 = 0.f;
        #pragma unroll
        for(int k = 0; k < 8; k++){ float v = A[q*64 + d0 + 8*k]; s += v; s2 += v * v; }
        #pragma unroll
        for(int m = 1; m <= 4; m <<= 1){ s += __shfl_xor(s, m, 64); s2 += __shfl_xor(s2, m, 64); }
        if(d0 == 0){
            float mu = s * (1.0f/64.0f);
            float var = s2 * (1.0f/64.0f) - mu * mu;
            mu8[q] = mu; rs8[q] = rsqrtf(fmaxf(var, 0.0f) + 1e-6f);
        }
    }
    __syncthreads();
    if(t < 64){
        int dd = t;
        float g2 = mlg[dd], bb = mlb[dd];
        float s = 0.f;
        #pragma unroll
        for(int qq = 0; qq < 8; qq++)
            s += (A[qq*64 + dd] - mu8[qq]) * rs8[qq] * g2 + bb;
        pooled[dd] = s;
    }
    __syncthreads();
    // ---- classifier: 2 output cols x 64-lane shuffle reduce ----
    if(t < 128){
        int c = t >> 6, d = t & 63;
        float v = pooled[d] * outw[d*2 + c];
        #pragma unroll
        for(int m = 32; m >= 1; m >>= 1) v += __shfl_xor(v, m, 64);
        if((t & 63) == 0) out[e*2 + c] = v + outb[c];
    }
}

extern "C" void kernel_launch(void* const* d_in, const int* in_sizes, int n_in,
                              void* d_out, int out_size, void* d_ws, size_t ws_size,
                              hipStream_t stream){
    (void)in_sizes; (void)n_in; (void)out_size; (void)ws_size;
    const float* features  = (const float*)d_in[0];
    const int*   src       = (const int*)d_in[1];
    const int*   dst       = (const int*)d_in[2];
    const int*   url       = (const int*)d_in[3];
    const float* gat_fc_w  = (const float*)d_in[4];
    const float* attn_l    = (const float*)d_in[5];
    const float* attn_r    = (const float*)d_in[6];
    const float* gat_res_w = (const float*)d_in[7];
    const float* gat_bias  = (const float*)d_in[8];
    const float* ln_g      = (const float*)d_in[9];
    const float* ln_b      = (const float*)d_in[10];
    const float* wq        = (const float*)d_in[11];
    const float* wk        = (const float*)d_in[12];
    const float* wv        = (const float*)d_in[13];
    const float* fc_w      = (const float*)d_in[14];
    const float* fc_b      = (const float*)d_in[15];
    const float* mha_ln_g  = (const float*)d_in[16];
    const float* mha_ln_b  = (const float*)d_in[17];
    const float* out_w     = (const float*)d_in[18];
    const float* out_b     = (const float*)d_in[19];

    char* base = (char*)d_ws;
    size_t cur = 0;
    auto alloc = [&](size_t nbytes) -> void* {
        void* p = base + cur;
        cur = (cur + nbytes + 255) & ~(size_t)255;
        return p;
    };
    float*        wl    = (float*)alloc(2048 * sizeof(float));   // transposed [8][256]
    float*        wr    = (float*)alloc(2048 * sizeof(float));
    int*          fill  = (int*)alloc(1024 * sizeof(int));
    int*          slist = (int*)alloc((size_t)1024 * 64 * sizeof(int));
    float*        gemb  = (float*)alloc((size_t)1024 * 512 * sizeof(float));
    unsigned int* wfcb  = (unsigned int*)alloc((size_t)256 * 512 * sizeof(unsigned short));
    unsigned int* wresb = (unsigned int*)alloc((size_t)256 * 512 * sizeof(unsigned short));

    hipMemsetAsync(fill, 0, 1024 * sizeof(int), stream);

    hipLaunchKernelGGL(k_scatter, dim3(1611), dim3(256), 0, stream, src, dst, url, fill, slist,
                       gat_fc_w, attn_l, attn_r, wl, wr, gat_fc_w, gat_res_w, wfcb, wresb);
    hipLaunchKernelGGL(k_gat,     dim3(1024), dim3(256), 0, stream, features, wfcb, wresb, gat_bias,
                       wl, wr, url, fill, slist, gemb);
    hipLaunchKernelGGL(k_mha,     dim3(1024), dim3(256), 0, stream, gemb, ln_g, ln_b,
                       wq, wk, wv, fc_w, fc_b, mha_ln_g, mha_ln_b, out_w, out_b,
                       (float*)d_out);
}

// Round 6
// 200.310 us; speedup vs baseline: 1.0384x; 1.0089x over previous
//
#include <hip/hip_runtime.h>
#include <math.h>

#define Nn 50000
#define Ee 400000
#define FSz 256
#define HD_ 512
#define Bb 1024
#define HSZ 2048

// World model (settled R5/R6): ALL float inputs fp32; OUTPUT fp32.
static __device__ __forceinline__ int clampi(int v, int lo, int hi){
    return v < lo ? lo : (v > hi ? hi : v);
}
static __device__ __forceinline__ unsigned short f2bf(float f){
    unsigned int u = __float_as_uint(f);
    unsigned int r = u + 0x7FFFu + ((u >> 16) & 1u);
    return (unsigned short)(r >> 16);
}
static __device__ __forceinline__ float bflo(unsigned int v){ return __uint_as_float(v << 16); }
static __device__ __forceinline__ float bfhi(unsigned int v){ return __uint_as_float(v & 0xFFFF0000u); }

// K1: blocks 0-1562: edge scatter via per-block LDS hash of url.
//     blocks 1563-1578: parallel fold attn -> wl,wr [8][256].
//     blocks 1579-1610: convert Wfc/Wres to packed bf16 pairs (col 2t|2t+1).
__global__ __launch_bounds__(256) void k_scatter(const int* __restrict__ src, const int* __restrict__ dst,
                                                 const int* __restrict__ url,
                                                 int* __restrict__ fill, int* __restrict__ slist,
                                                 const float* __restrict__ W,
                                                 const float* __restrict__ al,
                                                 const float* __restrict__ ar,
                                                 float* __restrict__ wl, float* __restrict__ wr,
                                                 const float* __restrict__ Wfc,
                                                 const float* __restrict__ Wres,
                                                 unsigned int* __restrict__ wfcb,
                                                 unsigned int* __restrict__ wresb){
    int t = threadIdx.x;
    if(blockIdx.x >= 1579){
        // bf16-pack Wfc and Wres: out[f*256+c] = pack(bf(W[f*512+2c]), bf(W[f*512+2c+1]))
        int bi = blockIdx.x - 1579;           // 0..31
        int m = bi >> 4;                      // 0: Wfc, 1: Wres
        const float2* Sf = (const float2*)(m ? Wres : Wfc);
        unsigned int* D = m ? wresb : wfcb;
        int base = (bi & 15) * 8192;          // 16 blocks x 8192 = 131072 pairs
        #pragma unroll
        for(int i = 0; i < 32; i++){
            int idx = base + i*256 + t;
            float2 v = Sf[idx];               // pair (2c, 2c+1) of row f
            D[idx] = ((unsigned int)f2bf(v.y) << 16) | (unsigned int)f2bf(v.x);
        }
        return;
    }
    if(blockIdx.x >= 1563){
        int bi = blockIdx.x - 1563;       // 0..15
        int wv = t >> 6, lane = t & 63;
        #pragma unroll
        for(int r = 0; r < 4; r++){
            int f = bi*16 + wv*4 + r;
            float pl[8], pr[8];
            #pragma unroll
            for(int h = 0; h < 8; h++){
                float w = W[f*512 + h*64 + lane];
                pl[h] = w * al[h*64 + lane];
                pr[h] = w * ar[h*64 + lane];
            }
            #pragma unroll
            for(int h = 0; h < 8; h++){
                #pragma unroll
                for(int m = 32; m >= 1; m >>= 1){
                    pl[h] += __shfl_xor(pl[h], m, 64);
                    pr[h] += __shfl_xor(pr[h], m, 64);
                }
            }
            #pragma unroll
            for(int h = 0; h < 8; h++){
                if(lane == h){ wl[h*256 + f] = pl[h]; wr[h*256 + f] = pr[h]; }
            }
        }
        return;
    }
    __shared__ int key[HSZ];
    __shared__ int chainhead[HSZ];
    __shared__ short nxt[Bb];
    for(int i = t; i < HSZ; i += 256){ key[i] = -1; chainhead[i] = -1; }
    __syncthreads();
    for(int b = t; b < Bb; b += 256){
        int n = clampi(url[b] - 1, 0, Nn - 1);
        int h = n & (HSZ - 1);
        while(true){
            int prev = atomicCAS(&key[h], -1, n);
            if(prev == -1 || prev == n) break;
            h = (h + 1) & (HSZ - 1);
        }
        int old = atomicExch(&chainhead[h], b);
        nxt[b] = (short)old;
    }
    __syncthreads();
    int e = blockIdx.x * 256 + t;
    if(e >= Ee) return;
    int d = dst[e];
    if((unsigned)d >= (unsigned)Nn) return;
    int h = d & (HSZ - 1);
    while(true){
        int k = key[h];
        if(k == -1) return;
        if(k == d) break;
        h = (h + 1) & (HSZ - 1);
    }
    int s = clampi(src[e], 0, Nn - 1);
    for(int b = chainhead[h]; b != -1; b = nxt[b]){
        int pos = atomicAdd(&fill[b], 1);
        if(pos < 64) slist[b*64 + pos] = s;
    }
}

// K2 (R17): FUSED gat+mha, 1 url-slot per block, grid 1024, lb(256,4).
// R5 evidence: k_mha 54.5 us (VALUBusy 58, Occ 31) and k_gat+k_scatter+gaps
// ~145 us; all dispatches latency-bound (HBM <1%, MfmaUtil 0). gat block u
// feeds ONLY mha block u -> the kernel boundary was an unnecessary global
// barrier. Fused: gather latency of one block hides under MHA VALU of
// co-resident blocks (same mechanism as R15's k_mha win); one fewer launch
// gap; no gemb round-trip. LDS 33.6 KB -> 4 blocks/CU.
__global__ __launch_bounds__(256, 4) void k_gatmha(
        const float* __restrict__ features,
        const unsigned int* __restrict__ Wfcb,   // [256][256] bf16 pairs
        const unsigned int* __restrict__ Wresb,
        const float* __restrict__ bias,
        const float* __restrict__ wl,            // [8][256] transposed
        const float* __restrict__ wr,
        const int* __restrict__ url,
        const int* __restrict__ fill, const int* __restrict__ slist,
        const float* __restrict__ lng, const float* __restrict__ lnb,
        const float* __restrict__ wq, const float* __restrict__ wk,
        const float* __restrict__ wvp, const float* __restrict__ fcw,
        const float* __restrict__ fcb, const float* __restrict__ mlg,
        const float* __restrict__ mlb, const float* __restrict__ outw,
        const float* __restrict__ outb, float* __restrict__ out){
    // ---- GAT-phase LDS ----
    __shared__ float cxs[8][256];    // 8 KB
    __shared__ float fres[256];      // 1 KB
    __shared__ float sew[64][8];     // 2 KB
    __shared__ float ser[8];
    __shared__ int   sslist[64];
    // ---- MHA-phase LDS ----
    __shared__ float A[512];                 // gat row -> sc -> yy
    __shared__ float xnF[512];               // fp32 LN1 out (residual)
    __shared__ unsigned short xnT[512];      // bf16 LN1 out, [d*8+q]
    __shared__ unsigned short qkb[8320];     // bf16 q | k ; k reused for fp32 partials
    __shared__ float mu8[8], rs8[8], pooled[64];

    int t = threadIdx.x;
    int lane = t & 63, wv = t >> 6;
    int u = blockIdx.x;

    for(int i = t; i < 64*8; i += 256) ((float*)sew)[i] = 0.f;

    float4 rwl[8], rwr[8];
    #pragma unroll
    for(int h = 0; h < 8; h++){
        rwl[h] = *(const float4*)&wl[h*256 + 4*lane];
        rwr[h] = *(const float4*)&wr[h*256 + 4*lane];
    }

    int dg = min(fill[u], 64);
    int nj = clampi(url[u] - 1, 0, Nn - 1);
    if(t < dg) sslist[t] = slist[u*64 + t];
    fres[t] = features[(size_t)nj * FSz + t];
    __syncthreads();

    // ---- pass A: wave-level dot products; tasks = dg edges + 1 er row
    for(int tau = wv; tau < dg + 1; tau += 4){
        int isEr = (tau == dg);
        int s = isEr ? nj : sslist[tau];
        float4 x = *(const float4*)(features + (size_t)s * FSz + 4*lane);
        float p[8];
        if(isEr){
            #pragma unroll
            for(int h = 0; h < 8; h++)
                p[h] = x.x*rwr[h].x + x.y*rwr[h].y + x.z*rwr[h].z + x.w*rwr[h].w;
        } else {
            #pragma unroll
            for(int h = 0; h < 8; h++)
                p[h] = x.x*rwl[h].x + x.y*rwl[h].y + x.z*rwl[h].z + x.w*rwl[h].w;
        }
        #pragma unroll
        for(int h = 0; h < 8; h++){
            #pragma unroll
            for(int m = 32; m >= 1; m >>= 1) p[h] += __shfl_xor(p[h], m, 64);
        }
        if(lane == 0){
            if(isEr){
                #pragma unroll
                for(int h = 0; h < 8; h++) ser[h] = p[h];
            } else {
                #pragma unroll
                for(int h = 0; h < 8; h++) sew[tau][h] = p[h];
            }
        }
    }
    __syncthreads();
    // ---- softmax per head: 8 lanes/head, shuffle-reduced over the group
    if(t < 64){
        int h = t >> 3, il = t & 7;   // lanes h*8..h*8+7 share head h
        float ern = ser[h];
        float m = -1e30f;
        for(int i = il; i < dg; i += 8){
            float v = sew[i][h] + ern;
            v = v > 0.f ? v : 0.2f * v;
            m = fmaxf(m, v);
        }
        #pragma unroll
        for(int mm = 1; mm <= 4; mm <<= 1) m = fmaxf(m, __shfl_xor(m, mm, 64));
        float sum = 0.f;
        for(int i = il; i < dg; i += 8){
            float v = sew[i][h] + ern;
            v = v > 0.f ? v : 0.2f * v;
            float w = expf(v - m);
            sum += w;
            sew[i][h] = w;
        }
        #pragma unroll
        for(int mm = 1; mm <= 4; mm <<= 1) sum += __shfl_xor(sum, mm, 64);
        float inv = 1.0f / fmaxf(sum, 1e-20f);
        for(int i = il; i < dg; i += 8) sew[i][h] *= inv;
    }
    __syncthreads();
    // ---- pass B: alpha-combine; unroll 4 -> 4 gathers in flight
    {
        float cx[8];
        #pragma unroll
        for(int h = 0; h < 8; h++) cx[h] = 0.f;
        for(int i = 0; i < dg; i += 4){
            float x[4];
            #pragma unroll
            for(int ii = 0; ii < 4; ii++){
                int idx = i + ii;
                int s = (idx < dg) ? sslist[idx] : 0;
                x[ii] = features[(size_t)s * FSz + t];
            }
            #pragma unroll
            for(int ii = 0; ii < 4; ii++){
                int idx = i + ii;
                const float* av = &sew[idx < 64 ? idx : 0][0];
                float xm = (idx < dg) ? x[ii] : 0.f;
                #pragma unroll
                for(int h = 0; h < 8; h++) cx[h] += av[h] * xm;
            }
        }
        #pragma unroll
        for(int h = 0; h < 8; h++) cxs[h][t] = cx[h];
    }
    __syncthreads();

    // ---- GEMV, bf16-pair weights; write gat row straight into A ----
    {
        int hh = t >> 5;
        float a0 = 0.f, a1 = 0.f;
        for(int f = 0; f < 256; f += 4){
            unsigned int w0 = Wfcb[(f+0)*256 + t];
            unsigned int w1 = Wfcb[(f+1)*256 + t];
            unsigned int w2 = Wfcb[(f+2)*256 + t];
            unsigned int w3 = Wfcb[(f+3)*256 + t];
            unsigned int r0 = Wresb[(f+0)*256 + t];
            unsigned int r1 = Wresb[(f+1)*256 + t];
            unsigned int r2 = Wresb[(f+2)*256 + t];
            unsigned int r3 = Wresb[(f+3)*256 + t];
            float4 c = *(const float4*)&cxs[hh][f];
            float4 x = *(const float4*)&fres[f];
            a0 += c.x*bflo(w0) + c.y*bflo(w1) + c.z*bflo(w2) + c.w*bflo(w3)
                + x.x*bflo(r0) + x.y*bflo(r1) + x.z*bflo(r2) + x.w*bflo(r3);
            a1 += c.x*bfhi(w0) + c.y*bfhi(w1) + c.z*bfhi(w2) + c.w*bfhi(w3)
                + x.x*bfhi(r0) + x.y*bfhi(r1) + x.z*bfhi(r2) + x.w*bfhi(r3);
        }
        A[2*t]     = a0 + bias[2*t];
        A[2*t + 1] = a1 + bias[2*t + 1];
    }
    __syncthreads();

    // ================= MHA phase (unchanged from R15 k_mha) =================
    // ---- LN1 stats: wave 0, 8 lanes per q-row, shuffle-reduced ----
    if(t < 64){
        int q = t >> 3, d0 = t & 7;
        float s = 0.f, s2 = 0.f;
        #pragma unroll
        for(int k = 0; k < 8; k++){ float v = A[q*64 + d0 + 8*k]; s += v; s2 += v * v; }
        #pragma unroll
        for(int m = 1; m <= 4; m <<= 1){ s += __shfl_xor(s, m, 64); s2 += __shfl_xor(s2, m, 64); }
        if(d0 == 0){
            float mu = s * (1.0f/64.0f);
            float var = s2 * (1.0f/64.0f) - mu * mu;
            mu8[q] = mu; rs8[q] = rsqrtf(fmaxf(var, 0.0f) + 1e-6f);
        }
    }
    __syncthreads();
    #pragma unroll
    for(int p = 0; p < 2; p++){
        int i = p*256 + t; int q = i >> 6, d = i & 63;
        float xv = (A[i] - mu8[q]) * rs8[q] * lng[d] + lnb[d];
        xnF[i] = xv;
        xnT[d*8 + q] = f2bf(xv);
    }
    __syncthreads();
    // ---- fused q,k,v projection; thread owns cols t, t+256 ----
    float aq0[8], aq1[8], ak0[8], ak1[8], av0[8], av1[8];
    #pragma unroll
    for(int r = 0; r < 8; r++){
        aq0[r]=0.f; aq1[r]=0.f; ak0[r]=0.f;
        ak1[r]=0.f; av0[r]=0.f; av1[r]=0.f;
    }
    #pragma unroll 2
    for(int d = 0; d < 64; d++){
        float q0 = wq[d*512 + t],  q1 = wq[d*512 + t + 256];
        float k0 = wk[d*512 + t],  k1 = wk[d*512 + t + 256];
        float v0 = wvp[d*512 + t], v1 = wvp[d*512 + t + 256];
        uint4 xp = *(const uint4*)&xnT[d*8];
        float xv[8] = { bflo(xp.x), bfhi(xp.x), bflo(xp.y), bfhi(xp.y),
                        bflo(xp.z), bfhi(xp.z), bflo(xp.w), bfhi(xp.w) };
        #pragma unroll
        for(int r = 0; r < 8; r++){
            aq0[r] += xv[r]*q0; aq1[r] += xv[r]*q1;
            ak0[r] += xv[r]*k0; ak1[r] += xv[r]*k1;
            av0[r] += xv[r]*v0; av1[r] += xv[r]*v1;
        }
    }
    #pragma unroll
    for(int qq = 0; qq < 8; qq++){
        qkb[qq*520 + t]              = f2bf(aq0[qq]);
        qkb[qq*520 + t + 256]        = f2bf(aq1[qq]);
        qkb[4160 + qq*520 + t]       = f2bf(ak0[qq]);
        qkb[4160 + qq*520 + t + 256] = f2bf(ak1[qq]);
    }
    __syncthreads();
    // ---- scores: 512 tasks, 2 per thread ----
    #pragma unroll
    for(int p = 0; p < 2; p++){
        int idx = p*256 + t;
        int nh = idx >> 6, qq = (idx >> 3) & 7, kk = idx & 7;
        const unsigned short* qrow = &qkb[qq*520 + nh*64];
        const unsigned short* krow = &qkb[4160 + kk*520 + nh*64];
        float s = 0.f;
        #pragma unroll
        for(int d8 = 0; d8 < 64; d8 += 8){
            uint4 qv = *(const uint4*)&qrow[d8];
            uint4 kv = *(const uint4*)&krow[d8];
            s += bflo(qv.x)*bflo(kv.x) + bfhi(qv.x)*bfhi(kv.x)
               + bflo(qv.y)*bflo(kv.y) + bfhi(qv.y)*bfhi(kv.y)
               + bflo(qv.z)*bflo(kv.z) + bfhi(qv.z)*bfhi(kv.z)
               + bflo(qv.w)*bflo(kv.w) + bfhi(qv.w)*bfhi(kv.w);
        }
        A[idx] = s * 0.125f;
    }
    __syncthreads();
    if(t < 64){
        int row = t;
        float mx = -1e30f;
        #pragma unroll
        for(int k = 0; k < 8; k++) mx = fmaxf(mx, A[row*8 + k]);
        float ev[8]; float s = 0.f;
        #pragma unroll
        for(int k = 0; k < 8; k++){ ev[k] = expf(A[row*8 + k] - mx); s += ev[k]; }
        float inv = 1.0f / s;
        #pragma unroll
        for(int k = 0; k < 8; k++) A[row*8 + k] = ev[k] * inv;
    }
    __syncthreads();
    // ---- attn @ v (v in registers) -> ov (bf16) into q regions ----
    {
        int nh0 = wv;
        #pragma unroll
        for(int qq = 0; qq < 8; qq++){
            const float* s0 = &A[nh0*64 + qq*8];
            const float* s1 = &A[(nh0+4)*64 + qq*8];
            float4 a0 = *(const float4*)s0, b0 = *(const float4*)(s0 + 4);
            float4 a1 = *(const float4*)s1, b1 = *(const float4*)(s1 + 4);
            float o0 = a0.x*av0[0] + a0.y*av0[1] + a0.z*av0[2] + a0.w*av0[3]
                     + b0.x*av0[4] + b0.y*av0[5] + b0.z*av0[6] + b0.w*av0[7];
            float o1 = a1.x*av1[0] + a1.y*av1[1] + a1.z*av1[2] + a1.w*av1[3]
                     + b1.x*av1[4] + b1.y*av1[5] + b1.z*av1[6] + b1.w*av1[7];
            qkb[qq*520 + t]       = f2bf(o0);
            qkb[qq*520 + t + 256] = f2bf(o1);
        }
    }
    __syncthreads();
    // ---- fc wave-split: wave wv owns k-range [wv*128, wv*128+128) ----
    {
        float* P = (float*)&qkb[4160];        // 4 waves x 512 fp32 partials
        int g = (t & 63) & 31;
        int qh = (t & 63) >> 5;
        int k0r = wv * 128;
        float a[4][2];
        #pragma unroll
        for(int jq = 0; jq < 4; jq++){ a[jq][0] = 0.f; a[jq][1] = 0.f; }
        const float2* fw2 = (const float2*)fcw;   // [512][32] float2
        for(int k = k0r; k < k0r + 128; k += 8){
            float2 f0 = fw2[(k+0)*32 + g];
            float2 f1 = fw2[(k+1)*32 + g];
            float2 f2 = fw2[(k+2)*32 + g];
            float2 f3 = fw2[(k+3)*32 + g];
            float2 f4 = fw2[(k+4)*32 + g];
            float2 f5 = fw2[(k+5)*32 + g];
            float2 f6 = fw2[(k+6)*32 + g];
            float2 f7 = fw2[(k+7)*32 + g];
            #pragma unroll
            for(int jq = 0; jq < 4; jq++){
                int qq = qh*4 + jq;
                uint4 op = *(const uint4*)&qkb[qq*520 + k];
                float x0 = bflo(op.x), x1 = bfhi(op.x), x2 = bflo(op.y), x3 = bfhi(op.y);
                float x4 = bflo(op.z), x5 = bfhi(op.z), x6 = bflo(op.w), x7 = bfhi(op.w);
                a[jq][0] += x0*f0.x + x1*f1.x + x2*f2.x + x3*f3.x + x4*f4.x + x5*f5.x + x6*f6.x + x7*f7.x;
                a[jq][1] += x0*f0.y + x1*f1.y + x2*f2.y + x3*f3.y + x4*f4.y + x5*f5.y + x6*f6.y + x7*f7.y;
            }
        }
        __syncthreads();
        #pragma unroll
        for(int jq = 0; jq < 4; jq++){
            int qq = qh*4 + jq;
            *(float2*)&P[wv*512 + qq*64 + 2*g] = make_float2(a[jq][0], a[jq][1]);
        }
        __syncthreads();
        #pragma unroll
        for(int p = 0; p < 2; p++){
            int o = p*256 + t; int dd = o & 63;
            A[o] = P[o] + P[512 + o] + P[1024 + o] + P[1536 + o] + fcb[dd] + xnF[o];
        }
    }
    __syncthreads();
    // ---- LN2 stats: wave-parallel like LN1 ----
    if(t < 64){
        int q = t >> 3, d0 = t & 7;
        float s = 0.f, s2 = 0.f;
        #pragma unroll
        for(int k = 0; k < 8; k++){ float v = A[q*64 + d0 + 8*k]; s += v; s2 += v * v; }
        #pragma unroll
        for(int m = 1; m <= 4; m <<= 1){ s += __shfl_xor(s, m, 64); s2 += __shfl_xor(s2, m, 64); }
        if(d0 == 0){
            float mu = s * (1.0f/64.0f);
            float var = s2 * (1.0f/64.0f) - mu * mu;
            mu8[q] = mu; rs8[q] = rsqrtf(fmaxf(var, 0.0f) + 1e-6f);
        }
    }
    __syncthreads();
    if(t < 64){
        int dd = t;
        float g2 = mlg[dd], bb = mlb[dd];
        float s = 0.f;
        #pragma unroll
        for(int qq = 0; qq < 8; qq++)
            s += (A[qq*64 + dd] - mu8[qq]) * rs8[qq] * g2 + bb;
        pooled[dd] = s;
    }
    __syncthreads();
    // ---- classifier: 2 output cols x 64-lane shuffle reduce ----
    if(t < 128){
        int c = t >> 6, d = t & 63;
        float v = pooled[d] * outw[d*2 + c];
        #pragma unroll
        for(int m = 32; m >= 1; m >>= 1) v += __shfl_xor(v, m, 64);
        if((t & 63) == 0) out[blockIdx.x*2 + c] = v + outb[c];
    }
}

extern "C" void kernel_launch(void* const* d_in, const int* in_sizes, int n_in,
                              void* d_out, int out_size, void* d_ws, size_t ws_size,
                              hipStream_t stream){
    (void)in_sizes; (void)n_in; (void)out_size; (void)ws_size;
    const float* features  = (const float*)d_in[0];
    const int*   src       = (const int*)d_in[1];
    const int*   dst       = (const int*)d_in[2];
    const int*   url       = (const int*)d_in[3];
    const float* gat_fc_w  = (const float*)d_in[4];
    const float* attn_l    = (const float*)d_in[5];
    const float* attn_r    = (const float*)d_in[6];
    const float* gat_res_w = (const float*)d_in[7];
    const float* gat_bias  = (const float*)d_in[8];
    const float* ln_g      = (const float*)d_in[9];
    const float* ln_b      = (const float*)d_in[10];
    const float* wq        = (const float*)d_in[11];
    const float* wk        = (const float*)d_in[12];
    const float* wv        = (const float*)d_in[13];
    const float* fc_w      = (const float*)d_in[14];
    const float* fc_b      = (const float*)d_in[15];
    const float* mha_ln_g  = (const float*)d_in[16];
    const float* mha_ln_b  = (const float*)d_in[17];
    const float* out_w     = (const float*)d_in[18];
    const float* out_b     = (const float*)d_in[19];

    char* base = (char*)d_ws;
    size_t cur = 0;
    auto alloc = [&](size_t nbytes) -> void* {
        void* p = base + cur;
        cur = (cur + nbytes + 255) & ~(size_t)255;
        return p;
    };
    float*        wl    = (float*)alloc(2048 * sizeof(float));   // transposed [8][256]
    float*        wr    = (float*)alloc(2048 * sizeof(float));
    int*          fill  = (int*)alloc(1024 * sizeof(int));
    int*          slist = (int*)alloc((size_t)1024 * 64 * sizeof(int));
    unsigned int* wfcb  = (unsigned int*)alloc((size_t)256 * 512 * sizeof(unsigned short));
    unsigned int* wresb = (unsigned int*)alloc((size_t)256 * 512 * sizeof(unsigned short));

    hipMemsetAsync(fill, 0, 1024 * sizeof(int), stream);

    hipLaunchKernelGGL(k_scatter, dim3(1611), dim3(256), 0, stream, src, dst, url, fill, slist,
                       gat_fc_w, attn_l, attn_r, wl, wr, gat_fc_w, gat_res_w, wfcb, wresb);
    hipLaunchKernelGGL(k_gatmha,  dim3(1024), dim3(256), 0, stream, features, wfcb, wresb, gat_bias,
                       wl, wr, url, fill, slist, ln_g, ln_b,
                       wq, wk, wv, fc_w, fc_b, mha_ln_g, mha_ln_b, out_w, out_b,
                       (float*)d_out);
}